// Round 3
// baseline (12400.259 us; speedup 1.0000x reference)
//
#include <hip/hip_runtime.h>
#include <math.h>

#define T_STEPS 256
#define BATCH   64
#define HID     300
#define G4      1200            // 4*HID
#define MTOT    (T_STEPS*BATCH) // 16384

// ---------------------------------------------------------------------------
// Kernel 0: transpose W_hh [1200][300] -> Wt [300][1200] (coalesced writes)
// ---------------------------------------------------------------------------
__global__ void k_wt(const float* __restrict__ W, float* __restrict__ Wt) {
    int idx = blockIdx.x * 256 + threadIdx.x;      // idx = k*1200 + r
    if (idx >= HID * G4) return;
    int k = idx / G4;
    int r = idx - k * G4;
    Wt[idx] = W[r * HID + k];
}

// ---------------------------------------------------------------------------
// Kernel 1: Xg[m][r] = sum_k E[tok[m]][k]*W_ih[r][k] + b_ih[r] + b_hh[r]
// fp32 tiled GEMM, BM=64 x BN=64 x BK=30, 256 thr, 4x4 per thread
// ---------------------------------------------------------------------------
#define BM 64
#define BN 64
#define BK 30

__global__ void __launch_bounds__(256)
k_xg(const int* __restrict__ tokens, const float* __restrict__ E,
     const float* __restrict__ Wih, const float* __restrict__ bih,
     const float* __restrict__ bhh, float* __restrict__ Xg) {
    __shared__ float As[BK][BM];
    __shared__ float Bs[BK][BN];
    __shared__ int   toks[BM];
    const int tid = threadIdx.x;
    const int m0 = blockIdx.x * BM;
    const int n0 = blockIdx.y * BN;
    if (tid < BM) toks[tid] = tokens[m0 + tid];
    __syncthreads();
    const int tm = tid >> 4;      // 0..15 -> rows tm*4..tm*4+3
    const int tn = tid & 15;      // 0..15 -> cols tn*4..tn*4+3
    float acc[4][4] = {};
    for (int k0 = 0; k0 < HID; k0 += BK) {
        for (int idx = tid; idx < BM * BK; idx += 256) {
            int row = idx / BK, kk = idx - row * BK;
            As[kk][row] = E[(size_t)toks[row] * HID + (k0 + kk)];
        }
        for (int idx = tid; idx < BN * BK; idx += 256) {
            int col = idx / BK, kk = idx - col * BK;
            int r = n0 + col;
            Bs[kk][col] = (r < G4) ? Wih[r * HID + (k0 + kk)] : 0.f;
        }
        __syncthreads();
#pragma unroll
        for (int kk = 0; kk < BK; ++kk) {
            const float4 av = *(const float4*)&As[kk][tm << 2];
            const float4 bv = *(const float4*)&Bs[kk][tn << 2];
            const float a[4] = {av.x, av.y, av.z, av.w};
            const float b[4] = {bv.x, bv.y, bv.z, bv.w};
#pragma unroll
            for (int i = 0; i < 4; ++i)
#pragma unroll
                for (int j = 0; j < 4; ++j)
                    acc[i][j] += a[i] * b[j];
        }
        __syncthreads();
    }
    const int rc = n0 + (tn << 2);
    if (rc < G4) {   // rc multiple of 4, rc+3 <= 1199
        float4 bias;
        bias.x = bih[rc + 0] + bhh[rc + 0];
        bias.y = bih[rc + 1] + bhh[rc + 1];
        bias.z = bih[rc + 2] + bhh[rc + 2];
        bias.w = bih[rc + 3] + bhh[rc + 3];
#pragma unroll
        for (int i = 0; i < 4; ++i) {
            int row = m0 + (tm << 2) + i;
            float4 v;
            v.x = acc[i][0] + bias.x;
            v.y = acc[i][1] + bias.y;
            v.z = acc[i][2] + bias.z;
            v.w = acc[i][3] + bias.w;
            *(float4*)&Xg[(size_t)row * G4 + rc] = v;
        }
    }
}

// ---------------------------------------------------------------------------
// Kernel 2: recurrent LSTM. One workgroup per batch element (64 WGs),
// 256 threads. h,c,gates in LDS; W_hh read (transposed, coalesced) from L2.
// ---------------------------------------------------------------------------
__global__ void __launch_bounds__(256)
k_lstm(const float* __restrict__ Xg, const float* __restrict__ Wt,
       const float* __restrict__ Wlin, const float* __restrict__ blin,
       float* __restrict__ out) {
    const int b   = blockIdx.x;
    const int tid = threadIdx.x;
    __shared__ float h_s[HID];
    __shared__ float c_s[HID];
    __shared__ float g_s[G4];
    __shared__ float red[2];
    for (int j = tid; j < HID; j += 256) { h_s[j] = 0.f; c_s[j] = 0.f; }
    if (tid < 2) red[tid] = 0.f;
    __syncthreads();

    const bool has5 = (tid + 1024) < G4;   // tid < 176

    for (int t = 0; t < T_STEPS; ++t) {
        const float* __restrict__ xrow = Xg + (size_t)(t * BATCH + b) * G4;
        float a0 = xrow[tid];
        float a1 = xrow[tid + 256];
        float a2 = xrow[tid + 512];
        float a3 = xrow[tid + 768];
        float a4 = has5 ? xrow[tid + 1024] : 0.f;
#pragma unroll 4
        for (int k = 0; k < HID; ++k) {
            const float hk = h_s[k];
            const float* __restrict__ w = Wt + k * G4 + tid;
            a0 += hk * w[0];
            a1 += hk * w[256];
            a2 += hk * w[512];
            a3 += hk * w[768];
            if (has5) a4 += hk * w[1024];
        }
        g_s[tid]       = a0;
        g_s[tid + 256] = a1;
        g_s[tid + 512] = a2;
        g_s[tid + 768] = a3;
        if (has5) g_s[tid + 1024] = a4;
        __syncthreads();
        for (int j = tid; j < HID; j += 256) {
            const float xi = g_s[j];
            const float xf = g_s[j + HID];
            const float xc = g_s[j + 2 * HID];
            const float xo = g_s[j + 3 * HID];
            const float ig = 1.f / (1.f + expf(-xi));
            const float fg = 1.f / (1.f + expf(-xf));
            const float gg = tanhf(xc);
            const float og = 1.f / (1.f + expf(-xo));
            const float c  = fg * c_s[j] + ig * gg;
            c_s[j] = c;
            h_s[j] = og * tanhf(c);
        }
        __syncthreads();
    }

    // final linear: out[b][u] = sum_j h[j]*W_lin[u][j] + b_lin[u]
    float p0 = 0.f, p1 = 0.f;
    for (int j = tid; j < HID; j += 256) {
        const float hv = h_s[j];
        p0 += hv * Wlin[j];
        p1 += hv * Wlin[HID + j];
    }
    atomicAdd(&red[0], p0);
    atomicAdd(&red[1], p1);
    __syncthreads();
    if (tid == 0) {
        out[b * 2 + 0] = red[0] + blin[0];
        out[b * 2 + 1] = red[1] + blin[1];
    }
}

// ---------------------------------------------------------------------------
extern "C" void kernel_launch(void* const* d_in, const int* in_sizes, int n_in,
                              void* d_out, int out_size, void* d_ws, size_t ws_size,
                              hipStream_t stream) {
    const int*   tokens = (const int*)  d_in[0];
    const float* E      = (const float*)d_in[1];
    const float* W_ih   = (const float*)d_in[2];
    const float* W_hh   = (const float*)d_in[3];
    const float* b_ih   = (const float*)d_in[4];
    const float* b_hh   = (const float*)d_in[5];
    const float* W_lin  = (const float*)d_in[6];
    const float* b_lin  = (const float*)d_in[7];
    float* out = (float*)d_out;

    char* ws = (char*)d_ws;
    float* Xg = (float*)ws;                                   // 16384*1200*4 = 78,643,200 B
    float* Wt = (float*)(ws + (size_t)MTOT * G4 * 4);         // +1,440,000 B

    // transpose W_hh
    k_wt<<<(HID * G4 + 255) / 256, 256, 0, stream>>>(W_hh, Wt);
    // precompute Xg (gather + GEMM + bias)
    dim3 gA(MTOT / BM, (G4 + BN - 1) / BN);   // 256 x 19
    k_xg<<<gA, 256, 0, stream>>>(tokens, E, W_ih, b_ih, b_hh, Xg);
    // recurrent part
    k_lstm<<<BATCH, 256, 0, stream>>>(Xg, Wt, W_lin, b_lin, out);
}

// Round 4
// 4352.025 us; speedup vs baseline: 2.8493x; 2.8493x over previous
//
#include <hip/hip_runtime.h>
#include <math.h>

#define T_STEPS 256
#define BATCH   64
#define HID     300
#define G4      1200            // 4*HID
#define MTOT    (T_STEPS*BATCH) // 16384

#define NSLICE  4
#define JS      75              // hidden j per slice
#define ROWS    300             // gate rows per WG (4 gates x 75)
#define KLDS    200             // k columns resident in LDS
#define KP_LDS  100             // fp16 pairs in LDS per row
#define KP_REG  50              // fp16 pairs in registers per row
#define NTHR    320             // 5 waves

#define XG_BYTES   ((size_t)MTOT * G4 * 4)            // 78,643,200
#define HBUF_ELT   ((size_t)NSLICE * 96)              // padded 96 fp32 per slice
#define HBUF_BYTES ((size_t)T_STEPS * BATCH * HBUF_ELT * 4)  // 25,165,824
#define CNT_BYTES  ((size_t)T_STEPS * BATCH * 8 * 4)  // 524,288 (32B stride)

typedef _Float16 half2v __attribute__((ext_vector_type(2)));

static __device__ __forceinline__ unsigned packh2(float a, float b) {
    half2v h; h.x = (_Float16)a; h.y = (_Float16)b;
    return __builtin_bit_cast(unsigned, h);
}
static __device__ __forceinline__ float dot2(unsigned w, unsigned h, float acc) {
#if __has_builtin(__builtin_amdgcn_fdot2)
    return __builtin_amdgcn_fdot2(__builtin_bit_cast(half2v, w),
                                  __builtin_bit_cast(half2v, h), acc, false);
#else
    half2v wv = __builtin_bit_cast(half2v, w);
    half2v hv = __builtin_bit_cast(half2v, h);
    return acc + (float)wv.x * (float)hv.x + (float)wv.y * (float)hv.y;
#endif
}

// ---------------------------------------------------------------------------
// Kernel 1: Xg[m][r] = sum_k E[tok[m]][k]*W_ih[r][k] + b_ih[r] + b_hh[r]
// ---------------------------------------------------------------------------
#define BM 64
#define BN 64
#define BK 30

__global__ void __launch_bounds__(256)
k_xg(const int* __restrict__ tokens, const float* __restrict__ E,
     const float* __restrict__ Wih, const float* __restrict__ bih,
     const float* __restrict__ bhh, float* __restrict__ Xg) {
    __shared__ float As[BK][BM];
    __shared__ float Bs[BK][BN];
    __shared__ int   toks[BM];
    const int tid = threadIdx.x;
    const int m0 = blockIdx.x * BM;
    const int n0 = blockIdx.y * BN;
    if (tid < BM) toks[tid] = tokens[m0 + tid];
    __syncthreads();
    const int tm = tid >> 4;
    const int tn = tid & 15;
    float acc[4][4] = {};
    for (int k0 = 0; k0 < HID; k0 += BK) {
        for (int idx = tid; idx < BM * BK; idx += 256) {
            int row = idx / BK, kk = idx - row * BK;
            As[kk][row] = E[(size_t)toks[row] * HID + (k0 + kk)];
        }
        for (int idx = tid; idx < BN * BK; idx += 256) {
            int col = idx / BK, kk = idx - col * BK;
            int r = n0 + col;
            Bs[kk][col] = (r < G4) ? Wih[r * HID + (k0 + kk)] : 0.f;
        }
        __syncthreads();
#pragma unroll
        for (int kk = 0; kk < BK; ++kk) {
            const float4 av = *(const float4*)&As[kk][tm << 2];
            const float4 bv = *(const float4*)&Bs[kk][tn << 2];
            const float a[4] = {av.x, av.y, av.z, av.w};
            const float b[4] = {bv.x, bv.y, bv.z, bv.w};
#pragma unroll
            for (int i = 0; i < 4; ++i)
#pragma unroll
                for (int j = 0; j < 4; ++j)
                    acc[i][j] += a[i] * b[j];
        }
        __syncthreads();
    }
    const int rc = n0 + (tn << 2);
    if (rc < G4) {
        float4 bias;
        bias.x = bih[rc + 0] + bhh[rc + 0];
        bias.y = bih[rc + 1] + bhh[rc + 1];
        bias.z = bih[rc + 2] + bhh[rc + 2];
        bias.w = bih[rc + 3] + bhh[rc + 3];
#pragma unroll
        for (int i = 0; i < 4; ++i) {
            int row = m0 + (tm << 2) + i;
            float4 v;
            v.x = acc[i][0] + bias.x;
            v.y = acc[i][1] + bias.y;
            v.z = acc[i][2] + bias.z;
            v.w = acc[i][3] + bias.w;
            *(float4*)&Xg[(size_t)row * G4 + rc] = v;
        }
    }
}

// ---------------------------------------------------------------------------
// Kernel 2: recurrent LSTM. 256 WGs = 64 batches x 4 slices; weights fp16
// resident in LDS (k<200) + VGPRs (k>=200); h exchanged via global + flags.
// bid = s*64 + b  =>  a batch's 4 WGs share bid%8 => same XCD (L2-local sync).
// ---------------------------------------------------------------------------
__global__ void __launch_bounds__(NTHR)
k_lstm(const float* __restrict__ Xg, const float* __restrict__ Whh,
       float* __restrict__ hbuf, unsigned* __restrict__ cnt) {
    const int bid = blockIdx.x;
    const int b   = bid & 63;
    const int s   = bid >> 6;
    const int tid = threadIdx.x;

    __shared__ unsigned Wp[ROWS * KP_LDS];   // 120,000 B
    __shared__ unsigned hp[152];             // fp16 h pairs (k-pairs 0..149)
    __shared__ float    g_s[ROWS + 4];

    const int lr   = tid;                                    // local row
    const int grow = (lr / JS) * HID + s * JS + (lr % JS);   // global gate row

    // --- one-time: stage W_hh (fp32 -> fp16 pairs) into LDS + registers ---
    for (int idx = tid; idx < ROWS * KP_LDS; idx += NTHR) {
        int row = idx / KP_LDS, p = idx - row * KP_LDS;
        int gr  = (row / JS) * HID + s * JS + (row % JS);
        const float2 w2 = *(const float2*)&Whh[(size_t)gr * HID + 2 * p];
        Wp[idx] = packh2(w2.x, w2.y);
    }
    unsigned wreg[KP_REG];
    if (lr < ROWS) {
        const float* wr = &Whh[(size_t)grow * HID + KLDS];
#pragma unroll
        for (int m = 0; m < 25; ++m) {
            float4 f = *(const float4*)&wr[4 * m];
            wreg[2 * m]     = packh2(f.x, f.y);
            wreg[2 * m + 1] = packh2(f.z, f.w);
        }
    }
    __syncthreads();

    float c_reg = 0.f;

    for (int t = 0; t < T_STEPS; ++t) {
        // Xg load depends only on t -> issue before the sync/spin
        float xg = 0.f;
        if (lr < ROWS) xg = Xg[(size_t)(t * BATCH + b) * G4 + grow];

        if (t > 0) {
            if (tid == 0) {
                const unsigned* e = &cnt[((t - 1) * BATCH + b) * 8];
                while (__hip_atomic_load(e, __ATOMIC_ACQUIRE,
                                         __HIP_MEMORY_SCOPE_AGENT) < NSLICE) {
                    __builtin_amdgcn_s_sleep(1);
                }
            }
            __syncthreads();
            if (tid < 150) {
                const size_t base = (size_t)((t - 1) * BATCH + b) * HBUF_ELT;
                int j0 = 2 * tid, j1 = j0 + 1;
                float a = __hip_atomic_load(&hbuf[base + (j0 / JS) * 96 + (j0 % JS)],
                                            __ATOMIC_RELAXED, __HIP_MEMORY_SCOPE_AGENT);
                float bb = __hip_atomic_load(&hbuf[base + (j1 / JS) * 96 + (j1 % JS)],
                                             __ATOMIC_RELAXED, __HIP_MEMORY_SCOPE_AGENT);
                hp[tid] = packh2(a, bb);
            }
            __syncthreads();
        } else {
            if (tid < 152) hp[tid] = 0u;
            __syncthreads();
        }

        // --- gate dot products ---
        if (lr < ROWS) {
            float acc = xg;
            const uint4* wrow = (const uint4*)&Wp[lr * KP_LDS];
            const uint4* hrow = (const uint4*)&hp[0];
#pragma unroll
            for (int i = 0; i < 25; ++i) {
                uint4 w = wrow[i];
                uint4 h = hrow[i];
                acc = dot2(w.x, h.x, acc);
                acc = dot2(w.y, h.y, acc);
                acc = dot2(w.z, h.z, acc);
                acc = dot2(w.w, h.w, acc);
            }
#pragma unroll
            for (int q = 0; q < KP_REG; ++q)
                acc = dot2(wreg[q], hp[KP_LDS + q], acc);
            g_s[lr] = acc;
        }
        __syncthreads();

        // --- elementwise LSTM cell for own 75 hidden units ---
        if (lr < JS) {
            const float xi = g_s[lr];
            const float xf = g_s[lr + JS];
            const float xc = g_s[lr + 2 * JS];
            const float xo = g_s[lr + 3 * JS];
            const float ig = 1.f / (1.f + expf(-xi));
            const float fg = 1.f / (1.f + expf(-xf));
            const float gg = tanhf(xc);
            const float og = 1.f / (1.f + expf(-xo));
            c_reg = fg * c_reg + ig * gg;
            const float hv = og * tanhf(c_reg);
            const size_t ob = (size_t)(t * BATCH + b) * HBUF_ELT + s * 96 + lr;
            __hip_atomic_store(&hbuf[ob], hv, __ATOMIC_RELAXED,
                               __HIP_MEMORY_SCOPE_AGENT);
            __threadfence();   // push h slice to agent-visible point
        }
        __syncthreads();
        if (tid == 0)
            __hip_atomic_fetch_add(&cnt[(t * BATCH + b) * 8], 1u,
                                   __ATOMIC_RELEASE, __HIP_MEMORY_SCOPE_AGENT);
    }
}

// ---------------------------------------------------------------------------
// Kernel 3: final linear from hbuf[T-1]
// ---------------------------------------------------------------------------
__global__ void __launch_bounds__(128)
k_fin(const float* __restrict__ hbuf, const float* __restrict__ Wlin,
      const float* __restrict__ blin, float* __restrict__ out) {
    const int b = blockIdx.x, tid = threadIdx.x;
    __shared__ float r0[128], r1[128];
    const size_t base = (size_t)((T_STEPS - 1) * BATCH + b) * HBUF_ELT;
    float p0 = 0.f, p1 = 0.f;
    for (int j = tid; j < HID; j += 128) {
        float h = hbuf[base + (j / JS) * 96 + (j % JS)];
        p0 += h * Wlin[j];
        p1 += h * Wlin[HID + j];
    }
    r0[tid] = p0; r1[tid] = p1;
    __syncthreads();
    for (int w = 64; w > 0; w >>= 1) {
        if (tid < w) { r0[tid] += r0[tid + w]; r1[tid] += r1[tid + w]; }
        __syncthreads();
    }
    if (tid == 0) {
        out[2 * b + 0] = r0[0] + blin[0];
        out[2 * b + 1] = r1[0] + blin[1];
    }
}

// ---------------------------------------------------------------------------
extern "C" void kernel_launch(void* const* d_in, const int* in_sizes, int n_in,
                              void* d_out, int out_size, void* d_ws, size_t ws_size,
                              hipStream_t stream) {
    const int*   tokens = (const int*)  d_in[0];
    const float* E      = (const float*)d_in[1];
    const float* W_ih   = (const float*)d_in[2];
    const float* W_hh   = (const float*)d_in[3];
    const float* b_ih   = (const float*)d_in[4];
    const float* b_hh   = (const float*)d_in[5];
    const float* W_lin  = (const float*)d_in[6];
    const float* b_lin  = (const float*)d_in[7];
    float* out = (float*)d_out;

    char* ws = (char*)d_ws;
    float*    Xg   = (float*)ws;
    float*    hbuf = (float*)(ws + XG_BYTES);
    unsigned* cnt  = (unsigned*)(ws + XG_BYTES + HBUF_BYTES);

    hipMemsetAsync(cnt, 0, CNT_BYTES, stream);   // capture-safe memset node

    dim3 gA(MTOT / BM, (G4 + BN - 1) / BN);      // 256 x 19
    k_xg<<<gA, 256, 0, stream>>>(tokens, E, W_ih, b_ih, b_hh, Xg);
    k_lstm<<<NSLICE * BATCH, NTHR, 0, stream>>>(Xg, W_hh, hbuf, cnt);
    k_fin<<<BATCH, 128, 0, stream>>>(hbuf, W_lin, b_lin, out);
}

// Round 5
// 1552.217 us; speedup vs baseline: 7.9887x; 2.8037x over previous
//
#include <hip/hip_runtime.h>
#include <math.h>

#define T_STEPS 256
#define BATCH   64
#define HID     300
#define G4      1200            // 4*HID
#define MTOT    (T_STEPS*BATCH) // 16384

#define NSLICE  4
#define JS      75              // hidden j per slice
#define ROWS    300             // gate rows per WG (4 gates x 75)
#define KLDS    200             // k columns resident in LDS
#define KP_LDS  100             // fp16 pairs in LDS per row
#define KP_REG  50              // fp16 pairs in registers per row
#define NTHR    320             // 5 waves

#define XG_BYTES   ((size_t)MTOT * G4 * 4)            // 78,643,200
#define HBUF_ELT   ((size_t)NSLICE * 96)              // padded 96 fp32 per slice
#define HBUF_BYTES ((size_t)T_STEPS * BATCH * HBUF_ELT * 4)  // 25,165,824
#define FLAG_BYTES ((size_t)T_STEPS * BATCH * 4 * 4)  // 262,144

typedef _Float16 half2v __attribute__((ext_vector_type(2)));

static __device__ __forceinline__ unsigned packh2(float a, float b) {
    half2v h; h.x = (_Float16)a; h.y = (_Float16)b;
    return __builtin_bit_cast(unsigned, h);
}
static __device__ __forceinline__ float dot2(unsigned w, unsigned h, float acc) {
#if __has_builtin(__builtin_amdgcn_fdot2)
    return __builtin_amdgcn_fdot2(__builtin_bit_cast(half2v, w),
                                  __builtin_bit_cast(half2v, h), acc, false);
#else
    half2v wv = __builtin_bit_cast(half2v, w);
    half2v hv = __builtin_bit_cast(half2v, h);
    return acc + (float)wv.x * (float)hv.x + (float)wv.y * (float)hv.y;
#endif
}

// ---------------------------------------------------------------------------
// Kernel 1: Xg[m][r] = sum_k E[tok[m]][k]*W_ih[r][k] + b_ih[r] + b_hh[r]
// ---------------------------------------------------------------------------
#define BM 64
#define BN 64
#define BK 30

__global__ void __launch_bounds__(256)
k_xg(const int* __restrict__ tokens, const float* __restrict__ E,
     const float* __restrict__ Wih, const float* __restrict__ bih,
     const float* __restrict__ bhh, float* __restrict__ Xg) {
    __shared__ float As[BK][BM];
    __shared__ float Bs[BK][BN];
    __shared__ int   toks[BM];
    const int tid = threadIdx.x;
    const int m0 = blockIdx.x * BM;
    const int n0 = blockIdx.y * BN;
    if (tid < BM) toks[tid] = tokens[m0 + tid];
    __syncthreads();
    const int tm = tid >> 4;
    const int tn = tid & 15;
    float acc[4][4] = {};
    for (int k0 = 0; k0 < HID; k0 += BK) {
        for (int idx = tid; idx < BM * BK; idx += 256) {
            int row = idx / BK, kk = idx - row * BK;
            As[kk][row] = E[(size_t)toks[row] * HID + (k0 + kk)];
        }
        for (int idx = tid; idx < BN * BK; idx += 256) {
            int col = idx / BK, kk = idx - col * BK;
            int r = n0 + col;
            Bs[kk][col] = (r < G4) ? Wih[r * HID + (k0 + kk)] : 0.f;
        }
        __syncthreads();
#pragma unroll
        for (int kk = 0; kk < BK; ++kk) {
            const float4 av = *(const float4*)&As[kk][tm << 2];
            const float4 bv = *(const float4*)&Bs[kk][tn << 2];
            const float a[4] = {av.x, av.y, av.z, av.w};
            const float b[4] = {bv.x, bv.y, bv.z, bv.w};
#pragma unroll
            for (int i = 0; i < 4; ++i)
#pragma unroll
                for (int j = 0; j < 4; ++j)
                    acc[i][j] += a[i] * b[j];
        }
        __syncthreads();
    }
    const int rc = n0 + (tn << 2);
    if (rc < G4) {
        float4 bias;
        bias.x = bih[rc + 0] + bhh[rc + 0];
        bias.y = bih[rc + 1] + bhh[rc + 1];
        bias.z = bih[rc + 2] + bhh[rc + 2];
        bias.w = bih[rc + 3] + bhh[rc + 3];
#pragma unroll
        for (int i = 0; i < 4; ++i) {
            int row = m0 + (tm << 2) + i;
            float4 v;
            v.x = acc[i][0] + bias.x;
            v.y = acc[i][1] + bias.y;
            v.z = acc[i][2] + bias.z;
            v.w = acc[i][3] + bias.w;
            *(float4*)&Xg[(size_t)row * G4 + rc] = v;
        }
    }
}

// ---------------------------------------------------------------------------
// Kernel 2: recurrent LSTM. 256 WGs = 64 batches x 4 slices; weights fp16
// resident in LDS (k<200) + VGPRs (k>=200). Cross-WG h exchange through LLC
// via RELAXED agent atomics (L2-bypass, no acquire/release fences).
// Ordering: h stores -> s_waitcnt vmcnt(0) per wave -> barrier -> token flag.
// ---------------------------------------------------------------------------
__global__ void __launch_bounds__(NTHR)
k_lstm(const float* __restrict__ Xg, const float* __restrict__ Whh,
       float* __restrict__ hbuf, unsigned* __restrict__ flag) {
    const int bid = blockIdx.x;
    const int b   = bid & 63;
    const int s   = bid >> 6;
    const int tid = threadIdx.x;

    __shared__ unsigned Wp[ROWS * KP_LDS];   // 120,000 B
    __shared__ unsigned hp[152];             // fp16 h pairs (k-pairs 0..149)
    __shared__ float    g_s[ROWS + 4];

    const int lr   = tid;                                    // local row
    const int grow = (lr / JS) * HID + s * JS + (lr % JS);   // global gate row

    // --- one-time: stage W_hh (fp32 -> fp16 pairs) into LDS + registers ---
    for (int idx = tid; idx < ROWS * KP_LDS; idx += NTHR) {
        int row = idx / KP_LDS, p = idx - row * KP_LDS;
        int gr  = (row / JS) * HID + s * JS + (row % JS);
        const float2 w2 = *(const float2*)&Whh[(size_t)gr * HID + 2 * p];
        Wp[idx] = packh2(w2.x, w2.y);
    }
    unsigned wreg[KP_REG];
    if (lr < ROWS) {
        const float* wr = &Whh[(size_t)grow * HID + KLDS];
#pragma unroll
        for (int m = 0; m < 25; ++m) {
            float4 f = *(const float4*)&wr[4 * m];
            wreg[2 * m]     = packh2(f.x, f.y);
            wreg[2 * m + 1] = packh2(f.z, f.w);
        }
    }
    __syncthreads();

    float c_reg = 0.f;

    for (int t = 0; t < T_STEPS; ++t) {
        // Xg load depends only on t -> issue before the spin
        float xg = 0.f;
        if (lr < ROWS) xg = Xg[(size_t)(t * BATCH + b) * G4 + grow];

        if (t > 0) {
            if (tid == 0) {
                const unsigned tok = (unsigned)t;   // producers wrote (t-1)+1
                const unsigned* f = &flag[((t - 1) * BATCH + b) * 4];
                for (;;) {
                    unsigned f0 = __hip_atomic_load(&f[0], __ATOMIC_RELAXED, __HIP_MEMORY_SCOPE_AGENT);
                    unsigned f1 = __hip_atomic_load(&f[1], __ATOMIC_RELAXED, __HIP_MEMORY_SCOPE_AGENT);
                    unsigned f2 = __hip_atomic_load(&f[2], __ATOMIC_RELAXED, __HIP_MEMORY_SCOPE_AGENT);
                    unsigned f3 = __hip_atomic_load(&f[3], __ATOMIC_RELAXED, __HIP_MEMORY_SCOPE_AGENT);
                    if ((((f0 ^ tok) | (f1 ^ tok)) | ((f2 ^ tok) | (f3 ^ tok))) == 0u) break;
                }
            }
            __syncthreads();
            if (tid < 150) {
                const size_t base = (size_t)((t - 1) * BATCH + b) * HBUF_ELT;
                int j0 = 2 * tid, j1 = j0 + 1;
                float a = __hip_atomic_load(&hbuf[base + (j0 / JS) * 96 + (j0 % JS)],
                                            __ATOMIC_RELAXED, __HIP_MEMORY_SCOPE_AGENT);
                float bb = __hip_atomic_load(&hbuf[base + (j1 / JS) * 96 + (j1 % JS)],
                                             __ATOMIC_RELAXED, __HIP_MEMORY_SCOPE_AGENT);
                hp[tid] = packh2(a, bb);
            }
            __syncthreads();
        } else {
            if (tid < 152) hp[tid] = 0u;
            __syncthreads();
        }

        // --- gate dot products ---
        if (lr < ROWS) {
            float acc = xg;
            const uint4* wrow = (const uint4*)&Wp[lr * KP_LDS];
            const uint4* hrow = (const uint4*)&hp[0];
#pragma unroll
            for (int i = 0; i < 25; ++i) {
                uint4 w = wrow[i];
                uint4 h = hrow[i];
                acc = dot2(w.x, h.x, acc);
                acc = dot2(w.y, h.y, acc);
                acc = dot2(w.z, h.z, acc);
                acc = dot2(w.w, h.w, acc);
            }
#pragma unroll
            for (int q = 0; q < KP_REG; ++q)
                acc = dot2(wreg[q], hp[KP_LDS + q], acc);
            g_s[lr] = acc;
        }
        __syncthreads();

        // --- elementwise LSTM cell for own 75 hidden units ---
        if (lr < JS) {
            const float xi = g_s[lr];
            const float xf = g_s[lr + JS];
            const float xc = g_s[lr + 2 * JS];
            const float xo = g_s[lr + 3 * JS];
            const float ig = 1.f / (1.f + expf(-xi));
            const float fg = 1.f / (1.f + expf(-xf));
            const float gg = tanhf(xc);
            const float og = 1.f / (1.f + expf(-xo));
            c_reg = fg * c_reg + ig * gg;
            const float hv = og * tanhf(c_reg);
            const size_t ob = (size_t)(t * BATCH + b) * HBUF_ELT + s * 96 + lr;
            __hip_atomic_store(&hbuf[ob], hv, __ATOMIC_RELAXED,
                               __HIP_MEMORY_SCOPE_AGENT);
        }
        // all waves: drain own stores to the coherence point, then publish
        asm volatile("s_waitcnt vmcnt(0)" ::: "memory");
        __syncthreads();
        if (tid == 0)
            __hip_atomic_store(&flag[(t * BATCH + b) * 4 + s], (unsigned)(t + 1),
                               __ATOMIC_RELAXED, __HIP_MEMORY_SCOPE_AGENT);
    }
}

// ---------------------------------------------------------------------------
// Kernel 3: final linear from hbuf[T-1]
// ---------------------------------------------------------------------------
__global__ void __launch_bounds__(128)
k_fin(const float* __restrict__ hbuf, const float* __restrict__ Wlin,
      const float* __restrict__ blin, float* __restrict__ out) {
    const int b = blockIdx.x, tid = threadIdx.x;
    __shared__ float r0[128], r1[128];
    const size_t base = (size_t)((T_STEPS - 1) * BATCH + b) * HBUF_ELT;
    float p0 = 0.f, p1 = 0.f;
    for (int j = tid; j < HID; j += 128) {
        float h = hbuf[base + (j / JS) * 96 + (j % JS)];
        p0 += h * Wlin[j];
        p1 += h * Wlin[HID + j];
    }
    r0[tid] = p0; r1[tid] = p1;
    __syncthreads();
    for (int w = 64; w > 0; w >>= 1) {
        if (tid < w) { r0[tid] += r0[tid + w]; r1[tid] += r1[tid + w]; }
        __syncthreads();
    }
    if (tid == 0) {
        out[2 * b + 0] = r0[0] + blin[0];
        out[2 * b + 1] = r1[0] + blin[1];
    }
}

// ---------------------------------------------------------------------------
extern "C" void kernel_launch(void* const* d_in, const int* in_sizes, int n_in,
                              void* d_out, int out_size, void* d_ws, size_t ws_size,
                              hipStream_t stream) {
    const int*   tokens = (const int*)  d_in[0];
    const float* E      = (const float*)d_in[1];
    const float* W_ih   = (const float*)d_in[2];
    const float* W_hh   = (const float*)d_in[3];
    const float* b_ih   = (const float*)d_in[4];
    const float* b_hh   = (const float*)d_in[5];
    const float* W_lin  = (const float*)d_in[6];
    const float* b_lin  = (const float*)d_in[7];
    float* out = (float*)d_out;

    char* ws = (char*)d_ws;
    float*    Xg   = (float*)ws;
    float*    hbuf = (float*)(ws + XG_BYTES);
    unsigned* flag = (unsigned*)(ws + XG_BYTES + HBUF_BYTES);

    hipMemsetAsync(flag, 0, FLAG_BYTES, stream);   // capture-safe memset node

    dim3 gA(MTOT / BM, (G4 + BN - 1) / BN);        // 256 x 19
    k_xg<<<gA, 256, 0, stream>>>(tokens, E, W_ih, b_ih, b_hh, Xg);
    k_lstm<<<NSLICE * BATCH, NTHR, 0, stream>>>(Xg, W_hh, hbuf, flag);
    k_fin<<<BATCH, 128, 0, stream>>>(hbuf, W_lin, b_lin, out);
}

// Round 6
// 1224.608 us; speedup vs baseline: 10.1259x; 1.2675x over previous
//
#include <hip/hip_runtime.h>
#include <math.h>

#define T_STEPS 256
#define BATCH   64
#define HID     300
#define G4      1200            // 4*HID
#define MTOT    (T_STEPS*BATCH) // 16384

#define NSLICE  4
#define JS      75              // hidden j per slice
#define ROWS    300             // gate rows per WG (4 gates x 75)
#define KP_LDS  100             // fp16 pairs in LDS per row (k<200)
#define KP_REG  50              // fp16 pairs in registers per row (k>=200)
#define NTHR    320             // 5 waves

#define KPAD    160             // padded k-pairs for packed buffers (320 cols)
#define HB_STRIDE 320           // words per (parity,b) slice, line-padded

#define XG_BYTES   ((size_t)MTOT * G4 * 4)              // 78,643,200
#define HB_BYTES   ((size_t)2 * BATCH * HB_STRIDE * 4)  // 163,840
#define APK_BYTES  ((size_t)MTOT * KPAD * 4)            // 10,485,760
#define WIHP_BYTES ((size_t)G4 * KPAD * 4)              // 768,000

typedef _Float16 half2v __attribute__((ext_vector_type(2)));

static __device__ __forceinline__ unsigned packh2(float a, float b) {
    half2v h; h.x = (_Float16)a; h.y = (_Float16)b;
    return __builtin_bit_cast(unsigned, h);
}
static __device__ __forceinline__ float dot2(unsigned w, unsigned h, float acc) {
#if __has_builtin(__builtin_amdgcn_fdot2)
    return __builtin_amdgcn_fdot2(__builtin_bit_cast(half2v, w),
                                  __builtin_bit_cast(half2v, h), acc, false);
#else
    half2v wv = __builtin_bit_cast(half2v, w);
    half2v hv = __builtin_bit_cast(half2v, h);
    return acc + (float)wv.x * (float)hv.x + (float)wv.y * (float)hv.y;
#endif
}

// ---------------------------------------------------------------------------
// Kernel 0a: gather+pack embeddings: Apk[m][p] = fp16pair(E[tok[m]][2p,2p+1]),
// zero-padded pairs 150..159. 8 rows per WG of 256.
// ---------------------------------------------------------------------------
__global__ void __launch_bounds__(256)
k_gather(const int* __restrict__ tokens, const float* __restrict__ E,
         unsigned* __restrict__ Apk) {
    const int base = blockIdx.x * 8;
    for (int idx = threadIdx.x; idx < 8 * KPAD; idx += 256) {
        int rl = idx / KPAD, p = idx - rl * KPAD;
        int m  = base + rl;
        unsigned w = 0u;
        if (p < 150) {
            const float2 v = *(const float2*)&E[(size_t)tokens[m] * HID + 2 * p];
            w = packh2(v.x, v.y);
        }
        Apk[(size_t)m * KPAD + p] = w;
    }
}

// ---------------------------------------------------------------------------
// Kernel 0b: pack W_ih rows the same way: Wihp[r][160]
// ---------------------------------------------------------------------------
__global__ void __launch_bounds__(256)
k_wpack(const float* __restrict__ Wih, unsigned* __restrict__ Wihp) {
    const int base = blockIdx.x * 8;
    for (int idx = threadIdx.x; idx < 8 * KPAD; idx += 256) {
        int rl = idx / KPAD, p = idx - rl * KPAD;
        int r  = base + rl;
        unsigned w = 0u;
        if (p < 150) {
            const float2 v = *(const float2*)&Wih[(size_t)r * HID + 2 * p];
            w = packh2(v.x, v.y);
        }
        Wihp[(size_t)r * KPAD + p] = w;
    }
}

// ---------------------------------------------------------------------------
// Kernel 1: Xg[m][r] = dot2-GEMM(Apk, Wihp) + b_ih[r] + b_hh[r]
// 64x64 tile, 256 thr, 4x4 acc, 16 k-pairs (32 cols) per K-tile, 10 tiles.
// ---------------------------------------------------------------------------
__global__ void __launch_bounds__(256)
k_xg(const unsigned* __restrict__ Apk, const unsigned* __restrict__ Wihp,
     const float* __restrict__ bih, const float* __restrict__ bhh,
     float* __restrict__ Xg) {
    __shared__ unsigned As_p[16][68];   // pad 68: 2-way banks, 16B-aligned reads
    __shared__ unsigned Bs_p[16][68];
    const int tid = threadIdx.x;
    const int m0 = blockIdx.x * 64;
    const int n0 = blockIdx.y * 64;
    const int tm = tid >> 4;
    const int tn = tid & 15;
    float acc[4][4] = {};
    for (int kp0 = 0; kp0 < KPAD; kp0 += 16) {
        int idx = tid;
#pragma unroll
        for (int it = 0; it < 4; ++it, idx += 256) {
            int m = idx >> 4, kp = idx & 15;
            As_p[kp][m] = Apk[(size_t)(m0 + m) * KPAD + kp0 + kp];
            int r = n0 + m;
            Bs_p[kp][m] = (r < G4) ? Wihp[(size_t)r * KPAD + kp0 + kp] : 0u;
        }
        __syncthreads();
#pragma unroll
        for (int kp = 0; kp < 16; ++kp) {
            const uint4 a4 = *(const uint4*)&As_p[kp][tm << 2];
            const uint4 b4 = *(const uint4*)&Bs_p[kp][tn << 2];
            const unsigned aa[4] = {a4.x, a4.y, a4.z, a4.w};
            const unsigned bb[4] = {b4.x, b4.y, b4.z, b4.w};
#pragma unroll
            for (int i = 0; i < 4; ++i)
#pragma unroll
                for (int j = 0; j < 4; ++j)
                    acc[i][j] = dot2(aa[i], bb[j], acc[i][j]);
        }
        __syncthreads();
    }
    const int rc = n0 + (tn << 2);
    if (rc < G4) {
        float4 bias;
        bias.x = bih[rc + 0] + bhh[rc + 0];
        bias.y = bih[rc + 1] + bhh[rc + 1];
        bias.z = bih[rc + 2] + bhh[rc + 2];
        bias.w = bih[rc + 3] + bhh[rc + 3];
#pragma unroll
        for (int i = 0; i < 4; ++i) {
            int row = m0 + (tm << 2) + i;
            float4 v;
            v.x = acc[i][0] + bias.x;
            v.y = acc[i][1] + bias.y;
            v.z = acc[i][2] + bias.z;
            v.w = acc[i][3] + bias.w;
            *(float4*)&Xg[(size_t)row * G4 + rc] = v;
        }
    }
}

// ---------------------------------------------------------------------------
// Kernel 2: recurrent LSTM. 256 WGs = 64 batches x 4 slices; weights fp16 in
// LDS (k<200) + VGPRs (k>=200). h exchanged as SELF-VALIDATING tagged words:
// word = fp16(h) | (t+1)<<16 in a parity-2 slot buffer hb[t&1][b][j].
// Consumer polls its own words directly -- no flags, no fences, no drain.
// Parity-2 safety: slice s overwrites slot t&1 (= h^(t-2)) only after reading
// all tags t, which implies every slice consumed h^(t-2).
// ---------------------------------------------------------------------------
__global__ void __launch_bounds__(NTHR)
k_lstm(const float* __restrict__ Xg, const float* __restrict__ Whh,
       unsigned* __restrict__ hb) {
    const int bid = blockIdx.x;
    const int b   = bid & 63;
    const int s   = bid >> 6;
    const int tid = threadIdx.x;

    __shared__ unsigned Wp[ROWS * KP_LDS];   // 120,000 B
    __shared__ unsigned hp[152];             // fp16 h pairs (k-pairs 0..149)
    __shared__ float    g_s[ROWS + 4];

    const int lr   = tid;                                    // local row
    const int grow = (lr / JS) * HID + s * JS + (lr % JS);   // global gate row

    // --- one-time: stage W_hh (fp32 -> fp16 pairs) into LDS + registers ---
    for (int idx = tid; idx < ROWS * KP_LDS; idx += NTHR) {
        int row = idx / KP_LDS, p = idx - row * KP_LDS;
        int gr  = (row / JS) * HID + s * JS + (row % JS);
        const float2 w2 = *(const float2*)&Whh[(size_t)gr * HID + 2 * p];
        Wp[idx] = packh2(w2.x, w2.y);
    }
    unsigned wreg[KP_REG];
    if (lr < ROWS) {
        const float* wr = &Whh[(size_t)grow * HID + 2 * KP_LDS];
#pragma unroll
        for (int m = 0; m < 25; ++m) {
            float4 f = *(const float4*)&wr[4 * m];
            wreg[2 * m]     = packh2(f.x, f.y);
            wreg[2 * m + 1] = packh2(f.z, f.w);
        }
    }
    __syncthreads();

    float c_reg = 0.f;

    for (int t = 0; t < T_STEPS; ++t) {
        // Xg load depends only on t -> issue before the spin
        float xg = 0.f;
        if (lr < ROWS) xg = Xg[(size_t)(t * BATCH + b) * G4 + grow];

        if (t > 0) {
            if (tid < 150) {
                const unsigned tag = (unsigned)t;   // h^(t-1) carries tag t
                const unsigned* src = &hb[(size_t)(((t - 1) & 1) * BATCH + b) * HB_STRIDE];
                unsigned w0, w1;
                do {
                    w0 = __hip_atomic_load(&src[2 * tid],     __ATOMIC_RELAXED, __HIP_MEMORY_SCOPE_AGENT);
                    w1 = __hip_atomic_load(&src[2 * tid + 1], __ATOMIC_RELAXED, __HIP_MEMORY_SCOPE_AGENT);
                } while ((w0 >> 16) != tag || (w1 >> 16) != tag);
                hp[tid] = (w0 & 0xFFFFu) | (w1 << 16);
            }
        } else {
            if (tid < 152) hp[tid] = 0u;
        }
        __syncthreads();

        // --- gate dot products ---
        if (lr < ROWS) {
            float acc = xg;
            const uint4* wrow = (const uint4*)&Wp[lr * KP_LDS];
            const uint4* hrow = (const uint4*)&hp[0];
#pragma unroll
            for (int i = 0; i < 25; ++i) {
                uint4 w = wrow[i];
                uint4 h = hrow[i];
                acc = dot2(w.x, h.x, acc);
                acc = dot2(w.y, h.y, acc);
                acc = dot2(w.z, h.z, acc);
                acc = dot2(w.w, h.w, acc);
            }
#pragma unroll
            for (int q = 0; q < KP_REG; ++q)
                acc = dot2(wreg[q], hp[KP_LDS + q], acc);
            g_s[lr] = acc;
        }
        __syncthreads();

        // --- elementwise LSTM cell for own 75 hidden units; publish tagged ---
        if (lr < JS) {
            const float xi = g_s[lr];
            const float xf = g_s[lr + JS];
            const float xc = g_s[lr + 2 * JS];
            const float xo = g_s[lr + 3 * JS];
            const float ig = 1.f / (1.f + expf(-xi));
            const float fg = 1.f / (1.f + expf(-xf));
            const float gg = tanhf(xc);
            const float og = 1.f / (1.f + expf(-xo));
            c_reg = fg * c_reg + ig * gg;
            const float hv = og * tanhf(c_reg);
            const unsigned hw = (unsigned)__builtin_bit_cast(unsigned short, (_Float16)hv)
                              | ((unsigned)(t + 1) << 16);
            __hip_atomic_store(&hb[(size_t)((t & 1) * BATCH + b) * HB_STRIDE + s * JS + lr],
                               hw, __ATOMIC_RELAXED, __HIP_MEMORY_SCOPE_AGENT);
        }
        // no trailing barrier: next-iteration poll (waits on ALL slices' tags,
        // incl. our own cell stores) + top barrier provide the ordering.
    }
}

// ---------------------------------------------------------------------------
// Kernel 3: final linear from hb parity slot (T-1)&1 = 1
// ---------------------------------------------------------------------------
__global__ void __launch_bounds__(128)
k_fin(const unsigned* __restrict__ hb, const float* __restrict__ Wlin,
      const float* __restrict__ blin, float* __restrict__ out) {
    const int b = blockIdx.x, tid = threadIdx.x;
    __shared__ float r0[128], r1[128];
    const unsigned* src = &hb[(size_t)(1 * BATCH + b) * HB_STRIDE];  // (255&1)=1
    float p0 = 0.f, p1 = 0.f;
    for (int j = tid; j < HID; j += 128) {
        const unsigned w = src[j];
        const float h = (float)__builtin_bit_cast(_Float16, (unsigned short)(w & 0xFFFFu));
        p0 += h * Wlin[j];
        p1 += h * Wlin[HID + j];
    }
    r0[tid] = p0; r1[tid] = p1;
    __syncthreads();
    for (int w = 64; w > 0; w >>= 1) {
        if (tid < w) { r0[tid] += r0[tid + w]; r1[tid] += r1[tid + w]; }
        __syncthreads();
    }
    if (tid == 0) {
        out[2 * b + 0] = r0[0] + blin[0];
        out[2 * b + 1] = r1[0] + blin[1];
    }
}

// ---------------------------------------------------------------------------
extern "C" void kernel_launch(void* const* d_in, const int* in_sizes, int n_in,
                              void* d_out, int out_size, void* d_ws, size_t ws_size,
                              hipStream_t stream) {
    const int*   tokens = (const int*)  d_in[0];
    const float* E      = (const float*)d_in[1];
    const float* W_ih   = (const float*)d_in[2];
    const float* W_hh   = (const float*)d_in[3];
    const float* b_ih   = (const float*)d_in[4];
    const float* b_hh   = (const float*)d_in[5];
    const float* W_lin  = (const float*)d_in[6];
    const float* b_lin  = (const float*)d_in[7];
    float* out = (float*)d_out;

    char* ws = (char*)d_ws;
    float*    Xg   = (float*)ws;
    unsigned* hb   = (unsigned*)(ws + XG_BYTES);
    unsigned* Apk  = (unsigned*)(ws + XG_BYTES + HB_BYTES);
    unsigned* Wihp = (unsigned*)(ws + XG_BYTES + HB_BYTES + APK_BYTES);
    // total ws use ~90.1 MB; hb needs no init (poison tag 0xAAAA != 1..256)

    k_gather<<<MTOT / 8, 256, 0, stream>>>(tokens, E, Apk);
    k_wpack<<<G4 / 8, 256, 0, stream>>>(W_ih, Wihp);
    dim3 gA(MTOT / 64, (G4 + 63) / 64);   // 256 x 19
    k_xg<<<gA, 256, 0, stream>>>(Apk, Wihp, b_ih, b_hh, Xg);
    k_lstm<<<NSLICE * BATCH, NTHR, 0, stream>>>(Xg, W_hh, hb);
    k_fin<<<BATCH, 128, 0, stream>>>(hb, W_lin, b_lin, out);
}